// Round 5
// baseline (9704.983 us; speedup 1.0000x reference)
//
#include <hip/hip_runtime.h>

#define B_ 64
#define S_ 512
#define D_ 512
#define H_ 1024

typedef __attribute__((ext_vector_type(8))) short bf16x8;
typedef __attribute__((ext_vector_type(4))) float f32x4;
typedef unsigned short u16;
typedef unsigned int u32;

#define MFMA(a, b, c) __builtin_amdgcn_mfma_f32_16x16x32_bf16(a, b, c, 0, 0, 0)

__device__ __forceinline__ u16 f2bf(float f) {
    u32 u = __float_as_uint(f);
    u += 0x7fffu + ((u >> 16) & 1u);
    return (u16)(u >> 16);
}
__device__ __forceinline__ float sigm(float x) { return 1.0f / (1.0f + __expf(-x)); }
__device__ __forceinline__ float tanh_f(float x) { return 1.0f - 2.0f / (__expf(2.0f * x) + 1.0f); }

__device__ __forceinline__ bf16x8 cvt8(const float* p) {
    float4 f0 = ((const float4*)p)[0];
    float4 f1 = ((const float4*)p)[1];
    bf16x8 v;
    v[0] = (short)f2bf(f0.x); v[1] = (short)f2bf(f0.y);
    v[2] = (short)f2bf(f0.z); v[3] = (short)f2bf(f0.w);
    v[4] = (short)f2bf(f1.x); v[5] = (short)f2bf(f1.y);
    v[6] = (short)f2bf(f1.z); v[7] = (short)f2bf(f1.w);
    return v;
}

// ---------------- prep: fp32 weights -> bf16 concatenated [Wih | Whh], K-contiguous ----
__global__ void prep_w(const float* __restrict__ Wih, const float* __restrict__ Whh,
                       u16* __restrict__ Wc, int Kx, int Kw, int total8) {
    int idx = blockIdx.x * 256 + threadIdx.x;
    if (idx >= total8) return;
    int kc8 = Kw >> 3;
    int n = idx / kc8;
    int kc = (idx - n * kc8) << 3;
    const float* src = (kc < Kx) ? (Wih + (size_t)n * Kx + kc)
                                 : (Whh + (size_t)n * (Kw - Kx) + (kc - Kx));
    *(bf16x8*)(Wc + (size_t)n * Kw + kc) = cvt8(src);
}

// ---------------- prep: biases + h-state init + barrier area zero ----------------
__global__ void prep_misc2(const float* __restrict__ h0in,
                           const float* __restrict__ bih0, const float* __restrict__ bhh0,
                           const float* __restrict__ bih1, const float* __restrict__ bhh1,
                           float* __restrict__ bias0, float* __restrict__ bias1,
                           u16* __restrict__ h0a, u16* __restrict__ h0b,
                           u16* __restrict__ h1a, u16* __restrict__ h1b,
                           int* __restrict__ bar) {
    int idx = blockIdx.x * 256 + threadIdx.x;
    if (idx < 1024) bar[idx] = 0;   // arrival counter + 8 release-flag lines
    if (idx < 4096) { bias0[idx] = bih0[idx] + bhh0[idx]; return; }
    if (idx < 8192) { int i = idx - 4096; bias1[i] = bih1[i] + bhh1[i]; return; }
    int r = idx - 8192;
    if (r >= 2 * B_ * H_) return;
    int l = r >> 16;
    int rr = r & 65535;
    u16 hb = f2bf(h0in[r]);
    if (l == 0) { h0a[rr] = hb; h0b[rr] = hb; }
    else        { h1a[rr] = hb; h1b[rr] = hb; }
}

// ---------------- persistent LSTM kernel: weights live in registers across all steps ---
// 256 blocks (1/CU) x 512 threads (8 waves). Block bk: col-group cgp=bk>>1 (8 h-cols ->
// 32 gate cols per layer), row-half mh=bk&1 (32 batch rows).
// Hierarchical grid barrier: leaders atomicAdd(RELEASE) an arrival counter that ONLY
// block 0 polls; block 0 then broadcasts the phase number to 8 flag lines; each leader
// polls its group's flag (read-only line, 32 pollers) then ACQUIRE (emits L2 inv ->
// cross-XCD visibility). All spins bounded (no hang). Stage-B fragment loads are issued
// before stage-A compute to hide LLC latency; x-part GEMM prefetched into barrier gap.
__global__ __launch_bounds__(512, 2) void lstm_persist(
    const float* __restrict__ x,
    const u16* __restrict__ W0c, const u16* __restrict__ W1c,
    const float* __restrict__ bias0, const float* __restrict__ bias1,
    const float* __restrict__ c0in,
    u16* __restrict__ h0a, u16* __restrict__ h0b,
    u16* __restrict__ h1a, u16* __restrict__ h1b,
    float* __restrict__ h1f,
    int* __restrict__ bar) {
    const int bk = blockIdx.x;
    const int cgp = bk >> 1;
    const int mh = bk & 1;
    const int tid = threadIdx.x;
    const int w = tid >> 6;
    const int lane = tid & 63;
    const int quad = lane >> 4;
    const int l16 = lane & 15;

    // gate columns for this lane's two N-tiles (4 gates x 8 h-cols per block)
    int gc[2];
    #pragma unroll
    for (int n = 0; n < 2; ++n) {
        int c = n * 16 + l16;
        gc[n] = (c >> 3) * 1024 + cgp * 8 + (c & 7);
    }

    // --- persistent weight fragments (loaded once, live in registers) ---
    // L0 x-part: wave w owns K = w*64 + {0,32};  L0 h-part: K = 512 + w*128 + {0..96}
    bf16x8 w0x[2][2], w0h[2][4];
    bf16x8 w1f[2][8];   // L1: K-slice 256 per wave
    #pragma unroll
    for (int n = 0; n < 2; ++n) {
        #pragma unroll
        for (int kf = 0; kf < 2; ++kf)
            w0x[n][kf] = *(const bf16x8*)(W0c + (size_t)gc[n] * 1536 + w * 64 + kf * 32 + quad * 8);
        #pragma unroll
        for (int kf = 0; kf < 4; ++kf)
            w0h[n][kf] = *(const bf16x8*)(W0c + (size_t)gc[n] * 1536 + 512 + w * 128 + kf * 32 + quad * 8);
        #pragma unroll
        for (int kf = 0; kf < 8; ++kf)
            w1f[n][kf] = *(const bf16x8*)(W1c + (size_t)gc[n] * 2048 + w * 256 + kf * 32 + quad * 8);
    }

    __shared__ float part[8 * 32 * 37];
    __shared__ float c0l[256], c1l[256];
    __shared__ float b0l[32], b1l[32];

    if (tid < 32) {
        int gg = tid >> 3, j = tid & 7;
        b0l[tid] = bias0[gg * 1024 + cgp * 8 + j];
        b1l[tid] = bias1[gg * 1024 + cgp * 8 + j];
    }
    if (tid < 256) {
        int b = tid >> 3, j = tid & 7;
        int gi = (mh * 32 + b) * 1024 + cgp * 8 + j;
        c0l[tid] = c0in[gi];
        c1l[tid] = c0in[65536 + gi];
    }
    __syncthreads();

    const int brow0 = mh * 32 + l16;
    const int brow1 = brow0 + 16;

    // x-part accumulators for the upcoming stage-A (computed one phase ahead)
    f32x4 xacc[2][2];
    #define XPART(t)                                                                 \
        {                                                                            \
            xacc[0][0] = (f32x4){0.f,0.f,0.f,0.f}; xacc[0][1] = (f32x4){0.f,0.f,0.f,0.f}; \
            xacc[1][0] = (f32x4){0.f,0.f,0.f,0.f}; xacc[1][1] = (f32x4){0.f,0.f,0.f,0.f}; \
            _Pragma("unroll")                                                        \
            for (int kf = 0; kf < 2; ++kf) {                                         \
                int k = w * 64 + kf * 32 + quad * 8;                                 \
                bf16x8 a0 = cvt8(x + (size_t)brow0 * 262144 + (t) * 512 + k);        \
                bf16x8 a1 = cvt8(x + (size_t)brow1 * 262144 + (t) * 512 + k);        \
                xacc[0][0] = MFMA(a0, w0x[0][kf], xacc[0][0]);                       \
                xacc[0][1] = MFMA(a0, w0x[1][kf], xacc[0][1]);                       \
                xacc[1][0] = MFMA(a1, w0x[0][kf], xacc[1][0]);                       \
                xacc[1][1] = MFMA(a1, w0x[1][kf], xacc[1][1]);                       \
            }                                                                        \
        }

    XPART(0);

    for (int p = 0; p <= S_; ++p) {
        const int rd = p & 1;
        const u16* h0r = rd ? h0b : h0a;
        u16*       h0w_ = rd ? h0a : h0b;
        const u16* h1r = rd ? h1b : h1a;
        u16*       h1w_ = rd ? h1a : h1b;

        // ---- hierarchical barrier wait: all blocks must have arrived for phase p-1 ----
        if (p > 0) {
            if (tid == 0) {
                if (bk == 0) {
                    int target = 256 * p;
                    for (int it = 0; it < 100000; ++it) {
                        if (__hip_atomic_load(&bar[0], __ATOMIC_RELAXED, __HIP_MEMORY_SCOPE_AGENT) >= target)
                            break;
                        __builtin_amdgcn_s_sleep(1);
                    }
                    (void)__hip_atomic_load(&bar[0], __ATOMIC_ACQUIRE, __HIP_MEMORY_SCOPE_AGENT);
                    #pragma unroll
                    for (int g = 0; g < 8; ++g)
                        __hip_atomic_store(&bar[(g + 1) * 64], p, __ATOMIC_RELEASE, __HIP_MEMORY_SCOPE_AGENT);
                } else {
                    const int g = bk >> 5;
                    for (int it = 0; it < 100000; ++it) {
                        if (__hip_atomic_load(&bar[(g + 1) * 64], __ATOMIC_RELAXED, __HIP_MEMORY_SCOPE_AGENT) >= p)
                            break;
                        __builtin_amdgcn_s_sleep(1);
                    }
                    (void)__hip_atomic_load(&bar[(g + 1) * 64], __ATOMIC_ACQUIRE, __HIP_MEMORY_SCOPE_AGENT);
                }
            }
            __syncthreads();
        }

        // ---- early-issue stage-B A-operand loads (hide LLC latency under stage A) ----
        bf16x8 pb0[8], pb1[8];
        if (p >= 1) {
            #pragma unroll
            for (int kf = 0; kf < 8; ++kf) {
                int k = w * 256 + kf * 32;
                const u16* src = (k < 1024) ? h0r : h1r;
                int ko = (k & 1023) + quad * 8;
                pb0[kf] = *(const bf16x8*)(src + brow0 * 1024 + ko);
                pb1[kf] = *(const bf16x8*)(src + brow1 * 1024 + ko);
            }
        }

        // ---------- stage A: layer 0, step p (h-part; x-part precomputed) ----------
        if (p < S_) {
            f32x4 acc00 = xacc[0][0], acc01 = xacc[0][1];
            f32x4 acc10 = xacc[1][0], acc11 = xacc[1][1];
            #pragma unroll
            for (int kf = 0; kf < 4; ++kf) {
                int ko = w * 128 + kf * 32 + quad * 8;
                bf16x8 a0 = *(const bf16x8*)(h0r + brow0 * 1024 + ko);
                bf16x8 a1 = *(const bf16x8*)(h0r + brow1 * 1024 + ko);
                acc00 = MFMA(a0, w0h[0][kf], acc00);
                acc01 = MFMA(a0, w0h[1][kf], acc01);
                acc10 = MFMA(a1, w0h[0][kf], acc10);
                acc11 = MFMA(a1, w0h[1][kf], acc11);
            }
            #pragma unroll
            for (int r = 0; r < 4; ++r) {
                int r0 = quad * 4 + r, r1 = 16 + quad * 4 + r;
                part[w * 1184 + r0 * 37 + l16]      = acc00[r];
                part[w * 1184 + r0 * 37 + 16 + l16] = acc01[r];
                part[w * 1184 + r1 * 37 + l16]      = acc10[r];
                part[w * 1184 + r1 * 37 + 16 + l16] = acc11[r];
            }
            __syncthreads();
            if (tid < 256) {
                int b = tid >> 3, j = tid & 7;
                float g4[4];
                #pragma unroll
                for (int gg = 0; gg < 4; ++gg) {
                    float s = b0l[gg * 8 + j];
                    #pragma unroll
                    for (int w8 = 0; w8 < 8; ++w8)
                        s += part[w8 * 1184 + b * 37 + gg * 8 + j];
                    g4[gg] = s;
                }
                float c = c0l[tid];
                float cn = sigm(g4[1]) * c + sigm(g4[0]) * tanh_f(g4[2]);
                float hn = sigm(g4[3]) * tanh_f(cn);
                c0l[tid] = cn;
                h0w_[(mh * 32 + b) * 1024 + cgp * 8 + j] = f2bf(hn);
            }
            __syncthreads();
        }

        // ---------- stage B: layer 1, step p-1 (A-operands preloaded) ----------
        if (p >= 1) {
            f32x4 acc00 = {0.f,0.f,0.f,0.f}, acc01 = {0.f,0.f,0.f,0.f};
            f32x4 acc10 = {0.f,0.f,0.f,0.f}, acc11 = {0.f,0.f,0.f,0.f};
            #pragma unroll
            for (int kf = 0; kf < 8; ++kf) {
                acc00 = MFMA(pb0[kf], w1f[0][kf], acc00);
                acc01 = MFMA(pb0[kf], w1f[1][kf], acc01);
                acc10 = MFMA(pb1[kf], w1f[0][kf], acc10);
                acc11 = MFMA(pb1[kf], w1f[1][kf], acc11);
            }
            #pragma unroll
            for (int r = 0; r < 4; ++r) {
                int r0 = quad * 4 + r, r1 = 16 + quad * 4 + r;
                part[w * 1184 + r0 * 37 + l16]      = acc00[r];
                part[w * 1184 + r0 * 37 + 16 + l16] = acc01[r];
                part[w * 1184 + r1 * 37 + l16]      = acc10[r];
                part[w * 1184 + r1 * 37 + 16 + l16] = acc11[r];
            }
            __syncthreads();
            if (tid < 256) {
                int b = tid >> 3, j = tid & 7;
                float g4[4];
                #pragma unroll
                for (int gg = 0; gg < 4; ++gg) {
                    float s = b1l[gg * 8 + j];
                    #pragma unroll
                    for (int w8 = 0; w8 < 8; ++w8)
                        s += part[w8 * 1184 + b * 37 + gg * 8 + j];
                    g4[gg] = s;
                }
                float c = c1l[tid];
                float cn = sigm(g4[1]) * c + sigm(g4[0]) * tanh_f(g4[2]);
                float hn = sigm(g4[3]) * tanh_f(cn);
                c1l[tid] = cn;
                int gi = (mh * 32 + b) * 1024 + cgp * 8 + j;
                h1w_[gi] = f2bf(hn);
                if (p == S_) h1f[gi] = hn;
            }
            __syncthreads();
        }

        // ---- barrier arrive (release), then prefetch next x-part during the gap ----
        if (p < S_) {
            if (tid == 0)
                __hip_atomic_fetch_add(&bar[0], 1, __ATOMIC_RELEASE, __HIP_MEMORY_SCOPE_AGENT);
            if (p + 1 < S_) XPART(p + 1);
        }
    }
}

// ---------------- final FC: out[b,o] = h1 . Wfc[o] + bfc[o] ----------------
__global__ void fc_k(const float* __restrict__ h1f, const float* __restrict__ Wfc,
                     const float* __restrict__ bfc, float* __restrict__ out) {
    int idx = blockIdx.x * 256 + threadIdx.x;
    if (idx >= 64 * 1000) return;
    int o = idx % 1000;
    int b = idx / 1000;
    const float4* hr = (const float4*)(h1f + b * H_);
    const float4* wr = (const float4*)(Wfc + (size_t)o * H_);
    float s = 0.f;
    #pragma unroll 4
    for (int k = 0; k < 256; ++k) {
        float4 a = hr[k];
        float4 w = wr[k];
        s += a.x * w.x + a.y * w.y + a.z * w.z + a.w * w.w;
    }
    out[idx] = s + bfc[o];
}

extern "C" void kernel_launch(void* const* d_in, const int* in_sizes, int n_in,
                              void* d_out, int out_size, void* d_ws, size_t ws_size,
                              hipStream_t stream) {
    const float* x    = (const float*)d_in[0];
    const float* h0in = (const float*)d_in[1];
    const float* c0in = (const float*)d_in[2];
    const float* Wih0 = (const float*)d_in[3];
    const float* Whh0 = (const float*)d_in[4];
    const float* bih0 = (const float*)d_in[5];
    const float* bhh0 = (const float*)d_in[6];
    const float* Wih1 = (const float*)d_in[7];
    const float* Whh1 = (const float*)d_in[8];
    const float* bih1 = (const float*)d_in[9];
    const float* bhh1 = (const float*)d_in[10];
    const float* Wfc  = (const float*)d_in[11];
    const float* bfc  = (const float*)d_in[12];
    float* out = (float*)d_out;

    char* ws = (char*)d_ws;
    size_t off = 0;
    auto alloc = [&](size_t bytes) {
        void* p = ws + off;
        off += (bytes + 255) & ~(size_t)255;
        return p;
    };
    u16* W0c   = (u16*)alloc((size_t)4096 * 1536 * 2);
    u16* W1c   = (u16*)alloc((size_t)4096 * 2048 * 2);
    float* bias0 = (float*)alloc(4096 * 4);
    float* bias1 = (float*)alloc(4096 * 4);
    u16* h0A   = (u16*)alloc(B_ * H_ * 2);
    u16* h0B   = (u16*)alloc(B_ * H_ * 2);
    u16* h1A   = (u16*)alloc(B_ * H_ * 2);
    u16* h1B   = (u16*)alloc(B_ * H_ * 2);
    float* h1f = (float*)alloc(B_ * H_ * 4);
    int* bar   = (int*)alloc(4096);

    prep_w<<<786432 / 256, 256, 0, stream>>>(Wih0, Whh0, W0c, 512, 1536, 786432);
    prep_w<<<1048576 / 256, 256, 0, stream>>>(Wih1, Whh1, W1c, 1024, 2048, 1048576);
    prep_misc2<<<(8192 + 2 * B_ * H_ + 255) / 256, 256, 0, stream>>>(
        h0in, bih0, bhh0, bih1, bhh1, bias0, bias1, h0A, h0B, h1A, h1B, bar);

    void* args[] = {(void*)&x, (void*)&W0c, (void*)&W1c, (void*)&bias0, (void*)&bias1,
                    (void*)&c0in, (void*)&h0A, (void*)&h0B, (void*)&h1A, (void*)&h1B,
                    (void*)&h1f, (void*)&bar};
    hipLaunchCooperativeKernel((void*)lstm_persist, dim3(256), dim3(512), args, 0, stream);

    fc_k<<<(64000 + 255) / 256, 256, 0, stream>>>(h1f, Wfc, bfc, out);
}

// Round 6
// 5877.007 us; speedup vs baseline: 1.6513x; 1.6513x over previous
//
#include <hip/hip_runtime.h>

#define B_ 64
#define S_ 512
#define D_ 512
#define H_ 1024

typedef __attribute__((ext_vector_type(8))) short bf16x8;
typedef __attribute__((ext_vector_type(4))) float f32x4;
typedef unsigned short u16;
typedef unsigned int u32;

#define MFMA(a, b, c) __builtin_amdgcn_mfma_f32_16x16x32_bf16(a, b, c, 0, 0, 0)

__device__ __forceinline__ u16 f2bf(float f) {
    u32 u = __float_as_uint(f);
    u += 0x7fffu + ((u >> 16) & 1u);
    return (u16)(u >> 16);
}
__device__ __forceinline__ float sigm(float x) { return 1.0f / (1.0f + __expf(-x)); }
__device__ __forceinline__ float tanh_f(float x) { return 1.0f - 2.0f / (__expf(2.0f * x) + 1.0f); }

__device__ __forceinline__ bf16x8 cvt8(const float* p) {
    float4 f0 = ((const float4*)p)[0];
    float4 f1 = ((const float4*)p)[1];
    bf16x8 v;
    v[0] = (short)f2bf(f0.x); v[1] = (short)f2bf(f0.y);
    v[2] = (short)f2bf(f0.z); v[3] = (short)f2bf(f0.w);
    v[4] = (short)f2bf(f1.x); v[5] = (short)f2bf(f1.y);
    v[6] = (short)f2bf(f1.z); v[7] = (short)f2bf(f1.w);
    return v;
}

// ---- LLC-direct access helpers: sc0 sc1 = bypass L1+L2, served by Infinity Cache ----
// (cross-XCD coherent WITHOUT any buffer_wbl2/buffer_inv cache maintenance)
__device__ __forceinline__ void llc_ld(bf16x8& d, const u16* p) {
    asm volatile("global_load_dwordx4 %0, %1, off sc0 sc1" : "=v"(d) : "v"(p));
}
__device__ __forceinline__ void vm0() {
    asm volatile("s_waitcnt vmcnt(0)" ::: "memory");
}
__device__ __forceinline__ void fence_frag(bf16x8& d) {
    asm volatile("" : "+v"(d));   // pin uses after the preceding vm0()
}
__device__ __forceinline__ void llc_st16(u16* p, u16 v) {
    u32 vv = v;
    asm volatile("global_store_short %0, %1, off sc0 sc1" :: "v"(p), "v"(vv) : "memory");
}

// ---------------- prep: fp32 weights -> bf16 concatenated [Wih | Whh], K-contiguous ----
__global__ void prep_w(const float* __restrict__ Wih, const float* __restrict__ Whh,
                       u16* __restrict__ Wc, int Kx, int Kw, int total8) {
    int idx = blockIdx.x * 256 + threadIdx.x;
    if (idx >= total8) return;
    int kc8 = Kw >> 3;
    int n = idx / kc8;
    int kc = (idx - n * kc8) << 3;
    const float* src = (kc < Kx) ? (Wih + (size_t)n * Kx + kc)
                                 : (Whh + (size_t)n * (Kw - Kx) + (kc - Kx));
    *(bf16x8*)(Wc + (size_t)n * Kw + kc) = cvt8(src);
}

// ---------------- prep: biases + h-state init + barrier counter zero ----------------
__global__ void prep_misc2(const float* __restrict__ h0in,
                           const float* __restrict__ bih0, const float* __restrict__ bhh0,
                           const float* __restrict__ bih1, const float* __restrict__ bhh1,
                           float* __restrict__ bias0, float* __restrict__ bias1,
                           u16* __restrict__ h0a, u16* __restrict__ h0b,
                           u16* __restrict__ h1a, u16* __restrict__ h1b,
                           int* __restrict__ bar) {
    int idx = blockIdx.x * 256 + threadIdx.x;
    if (idx < 1024) bar[idx] = 0;
    if (idx < 4096) { bias0[idx] = bih0[idx] + bhh0[idx]; return; }
    if (idx < 8192) { int i = idx - 4096; bias1[i] = bih1[i] + bhh1[i]; return; }
    int r = idx - 8192;
    if (r >= 2 * B_ * H_) return;
    int l = r >> 16;
    int rr = r & 65535;
    u16 hb = f2bf(h0in[r]);
    if (l == 0) { h0a[rr] = hb; h0b[rr] = hb; }
    else        { h1a[rr] = hb; h1b[rr] = hb; }
}

// ---------------- persistent LSTM kernel: weights live in registers across all steps ---
// 256 blocks (1/CU) x 512 threads (8 waves). Block bk: col-group cgp=bk>>1 (8 h-cols ->
// 32 gate cols per layer), row-half mh=bk&1 (32 batch rows).
// Cross-block h-state goes through LLC-direct (sc0 sc1) loads/stores -> ZERO cache
// maintenance; flat grid barrier is pure relaxed atomics (visibility guaranteed by the
// write-through stores + vmcnt drain at __syncthreads before arrive). Spins bounded.
__global__ __launch_bounds__(512, 2) void lstm_persist(
    const float* __restrict__ x,
    const u16* __restrict__ W0c, const u16* __restrict__ W1c,
    const float* __restrict__ bias0, const float* __restrict__ bias1,
    const float* __restrict__ c0in,
    u16* __restrict__ h0a, u16* __restrict__ h0b,
    u16* __restrict__ h1a, u16* __restrict__ h1b,
    float* __restrict__ h1f,
    int* __restrict__ bar) {
    const int bk = blockIdx.x;
    const int cgp = bk >> 1;
    const int mh = bk & 1;
    const int tid = threadIdx.x;
    const int w = tid >> 6;
    const int lane = tid & 63;
    const int quad = lane >> 4;
    const int l16 = lane & 15;

    int gc[2];
    #pragma unroll
    for (int n = 0; n < 2; ++n) {
        int c = n * 16 + l16;
        gc[n] = (c >> 3) * 1024 + cgp * 8 + (c & 7);
    }

    // --- persistent weight fragments (loaded once, live in registers) ---
    bf16x8 w0x[2][2], w0h[2][4];
    bf16x8 w1f[2][8];
    #pragma unroll
    for (int n = 0; n < 2; ++n) {
        #pragma unroll
        for (int kf = 0; kf < 2; ++kf)
            w0x[n][kf] = *(const bf16x8*)(W0c + (size_t)gc[n] * 1536 + w * 64 + kf * 32 + quad * 8);
        #pragma unroll
        for (int kf = 0; kf < 4; ++kf)
            w0h[n][kf] = *(const bf16x8*)(W0c + (size_t)gc[n] * 1536 + 512 + w * 128 + kf * 32 + quad * 8);
        #pragma unroll
        for (int kf = 0; kf < 8; ++kf)
            w1f[n][kf] = *(const bf16x8*)(W1c + (size_t)gc[n] * 2048 + w * 256 + kf * 32 + quad * 8);
    }

    __shared__ float part[8 * 32 * 37];
    __shared__ float c0l[256], c1l[256];
    __shared__ float b0l[32], b1l[32];

    if (tid < 32) {
        int gg = tid >> 3, j = tid & 7;
        b0l[tid] = bias0[gg * 1024 + cgp * 8 + j];
        b1l[tid] = bias1[gg * 1024 + cgp * 8 + j];
    }
    if (tid < 256) {
        int b = tid >> 3, j = tid & 7;
        int gi = (mh * 32 + b) * 1024 + cgp * 8 + j;
        c0l[tid] = c0in[gi];
        c1l[tid] = c0in[65536 + gi];
    }
    __syncthreads();

    const int brow0 = mh * 32 + l16;
    const int brow1 = brow0 + 16;

    // x-part accumulators (plain cached loads -- L2 stays warm: no buffer_inv anywhere)
    f32x4 xacc[2][2];
    #define XPART(t)                                                                 \
        {                                                                            \
            xacc[0][0] = (f32x4){0.f,0.f,0.f,0.f}; xacc[0][1] = (f32x4){0.f,0.f,0.f,0.f}; \
            xacc[1][0] = (f32x4){0.f,0.f,0.f,0.f}; xacc[1][1] = (f32x4){0.f,0.f,0.f,0.f}; \
            _Pragma("unroll")                                                        \
            for (int kf = 0; kf < 2; ++kf) {                                         \
                int k = w * 64 + kf * 32 + quad * 8;                                 \
                bf16x8 a0 = cvt8(x + (size_t)brow0 * 262144 + (t) * 512 + k);        \
                bf16x8 a1 = cvt8(x + (size_t)brow1 * 262144 + (t) * 512 + k);        \
                xacc[0][0] = MFMA(a0, w0x[0][kf], xacc[0][0]);                       \
                xacc[0][1] = MFMA(a0, w0x[1][kf], xacc[0][1]);                       \
                xacc[1][0] = MFMA(a1, w0x[0][kf], xacc[1][0]);                       \
                xacc[1][1] = MFMA(a1, w0x[1][kf], xacc[1][1]);                       \
            }                                                                        \
        }

    XPART(0);

    for (int p = 0; p <= S_; ++p) {
        const int rd = p & 1;
        const u16* h0r = rd ? h0b : h0a;
        u16*       h0w_ = rd ? h0a : h0b;
        const u16* h1r = rd ? h1b : h1a;
        u16*       h1w_ = rd ? h1a : h1b;

        // ---- flat barrier wait (relaxed polls only; bounded -> no hang possible) ----
        if (p > 0) {
            if (tid == 0) {
                int target = 256 * p;
                for (int it = 0; it < 20000; ++it) {
                    if (__hip_atomic_load(&bar[0], __ATOMIC_RELAXED, __HIP_MEMORY_SCOPE_AGENT) >= target)
                        break;
                    __builtin_amdgcn_s_sleep(1);
                }
            }
            __syncthreads();
        }

        // ---- issue stage-A loads, wait, then issue stage-B loads (overlap A compute) --
        bf16x8 a0[4], a1[4];
        if (p < S_) {
            #pragma unroll
            for (int kf = 0; kf < 4; ++kf) {
                int ko = w * 128 + kf * 32 + quad * 8;
                llc_ld(a0[kf], h0r + brow0 * 1024 + ko);
                llc_ld(a1[kf], h0r + brow1 * 1024 + ko);
            }
            vm0();
            #pragma unroll
            for (int kf = 0; kf < 4; ++kf) { fence_frag(a0[kf]); fence_frag(a1[kf]); }
        }
        bf16x8 pb0[8], pb1[8];
        if (p >= 1) {
            #pragma unroll
            for (int kf = 0; kf < 8; ++kf) {
                int k = w * 256 + kf * 32;
                const u16* src = (k < 1024) ? h0r : h1r;
                int ko = (k & 1023) + quad * 8;
                llc_ld(pb0[kf], src + brow0 * 1024 + ko);
                llc_ld(pb1[kf], src + brow1 * 1024 + ko);
            }
        }

        // ---------- stage A: layer 0, step p (h-part; x-part precomputed) ----------
        if (p < S_) {
            f32x4 acc00 = xacc[0][0], acc01 = xacc[0][1];
            f32x4 acc10 = xacc[1][0], acc11 = xacc[1][1];
            #pragma unroll
            for (int kf = 0; kf < 4; ++kf) {
                acc00 = MFMA(a0[kf], w0h[0][kf], acc00);
                acc01 = MFMA(a0[kf], w0h[1][kf], acc01);
                acc10 = MFMA(a1[kf], w0h[0][kf], acc10);
                acc11 = MFMA(a1[kf], w0h[1][kf], acc11);
            }
            #pragma unroll
            for (int r = 0; r < 4; ++r) {
                int r0 = quad * 4 + r, r1 = 16 + quad * 4 + r;
                part[w * 1184 + r0 * 37 + l16]      = acc00[r];
                part[w * 1184 + r0 * 37 + 16 + l16] = acc01[r];
                part[w * 1184 + r1 * 37 + l16]      = acc10[r];
                part[w * 1184 + r1 * 37 + 16 + l16] = acc11[r];
            }
            __syncthreads();
            if (tid < 256) {
                int b = tid >> 3, j = tid & 7;
                float g4[4];
                #pragma unroll
                for (int gg = 0; gg < 4; ++gg) {
                    float s = b0l[gg * 8 + j];
                    #pragma unroll
                    for (int w8 = 0; w8 < 8; ++w8)
                        s += part[w8 * 1184 + b * 37 + gg * 8 + j];
                    g4[gg] = s;
                }
                float c = c0l[tid];
                float cn = sigm(g4[1]) * c + sigm(g4[0]) * tanh_f(g4[2]);
                float hn = sigm(g4[3]) * tanh_f(cn);
                c0l[tid] = cn;
                llc_st16(h0w_ + (mh * 32 + b) * 1024 + cgp * 8 + j, f2bf(hn));
            }
            __syncthreads();
        }

        // ---------- stage B: layer 1, step p-1 (A-operands already in flight) ----------
        if (p >= 1) {
            vm0();
            #pragma unroll
            for (int kf = 0; kf < 8; ++kf) { fence_frag(pb0[kf]); fence_frag(pb1[kf]); }
            f32x4 acc00 = {0.f,0.f,0.f,0.f}, acc01 = {0.f,0.f,0.f,0.f};
            f32x4 acc10 = {0.f,0.f,0.f,0.f}, acc11 = {0.f,0.f,0.f,0.f};
            #pragma unroll
            for (int kf = 0; kf < 8; ++kf) {
                acc00 = MFMA(pb0[kf], w1f[0][kf], acc00);
                acc01 = MFMA(pb0[kf], w1f[1][kf], acc01);
                acc10 = MFMA(pb1[kf], w1f[0][kf], acc10);
                acc11 = MFMA(pb1[kf], w1f[1][kf], acc11);
            }
            #pragma unroll
            for (int r = 0; r < 4; ++r) {
                int r0 = quad * 4 + r, r1 = 16 + quad * 4 + r;
                part[w * 1184 + r0 * 37 + l16]      = acc00[r];
                part[w * 1184 + r0 * 37 + 16 + l16] = acc01[r];
                part[w * 1184 + r1 * 37 + l16]      = acc10[r];
                part[w * 1184 + r1 * 37 + 16 + l16] = acc11[r];
            }
            __syncthreads();
            if (tid < 256) {
                int b = tid >> 3, j = tid & 7;
                float g4[4];
                #pragma unroll
                for (int gg = 0; gg < 4; ++gg) {
                    float s = b1l[gg * 8 + j];
                    #pragma unroll
                    for (int w8 = 0; w8 < 8; ++w8)
                        s += part[w8 * 1184 + b * 37 + gg * 8 + j];
                    g4[gg] = s;
                }
                float c = c1l[tid];
                float cn = sigm(g4[1]) * c + sigm(g4[0]) * tanh_f(g4[2]);
                float hn = sigm(g4[3]) * tanh_f(cn);
                c1l[tid] = cn;
                int gi = (mh * 32 + b) * 1024 + cgp * 8 + j;
                llc_st16(h1w_ + gi, f2bf(hn));
                if (p == S_) h1f[gi] = hn;
            }
            __syncthreads();
        }

        // ---- barrier arrive (relaxed; stores already drained to LLC by __syncthreads'
        //      vmcnt(0) since they are write-through), then prefetch next x-part ----
        if (p < S_) {
            if (tid == 0)
                __hip_atomic_fetch_add(&bar[0], 1, __ATOMIC_RELAXED, __HIP_MEMORY_SCOPE_AGENT);
            if (p + 1 < S_) XPART(p + 1);
        }
    }
}

// ---------------- final FC: out[b,o] = h1 . Wfc[o] + bfc[o] ----------------
__global__ void fc_k(const float* __restrict__ h1f, const float* __restrict__ Wfc,
                     const float* __restrict__ bfc, float* __restrict__ out) {
    int idx = blockIdx.x * 256 + threadIdx.x;
    if (idx >= 64 * 1000) return;
    int o = idx % 1000;
    int b = idx / 1000;
    const float4* hr = (const float4*)(h1f + b * H_);
    const float4* wr = (const float4*)(Wfc + (size_t)o * H_);
    float s = 0.f;
    #pragma unroll 4
    for (int k = 0; k < 256; ++k) {
        float4 a = hr[k];
        float4 w = wr[k];
        s += a.x * w.x + a.y * w.y + a.z * w.z + a.w * w.w;
    }
    out[idx] = s + bfc[o];
}

extern "C" void kernel_launch(void* const* d_in, const int* in_sizes, int n_in,
                              void* d_out, int out_size, void* d_ws, size_t ws_size,
                              hipStream_t stream) {
    const float* x    = (const float*)d_in[0];
    const float* h0in = (const float*)d_in[1];
    const float* c0in = (const float*)d_in[2];
    const float* Wih0 = (const float*)d_in[3];
    const float* Whh0 = (const float*)d_in[4];
    const float* bih0 = (const float*)d_in[5];
    const float* bhh0 = (const float*)d_in[6];
    const float* Wih1 = (const float*)d_in[7];
    const float* Whh1 = (const float*)d_in[8];
    const float* bih1 = (const float*)d_in[9];
    const float* bhh1 = (const float*)d_in[10];
    const float* Wfc  = (const float*)d_in[11];
    const float* bfc  = (const float*)d_in[12];
    float* out = (float*)d_out;

    char* ws = (char*)d_ws;
    size_t off = 0;
    auto alloc = [&](size_t bytes) {
        void* p = ws + off;
        off += (bytes + 255) & ~(size_t)255;
        return p;
    };
    u16* W0c   = (u16*)alloc((size_t)4096 * 1536 * 2);
    u16* W1c   = (u16*)alloc((size_t)4096 * 2048 * 2);
    float* bias0 = (float*)alloc(4096 * 4);
    float* bias1 = (float*)alloc(4096 * 4);
    u16* h0A   = (u16*)alloc(B_ * H_ * 2);
    u16* h0B   = (u16*)alloc(B_ * H_ * 2);
    u16* h1A   = (u16*)alloc(B_ * H_ * 2);
    u16* h1B   = (u16*)alloc(B_ * H_ * 2);
    float* h1f = (float*)alloc(B_ * H_ * 4);
    int* bar   = (int*)alloc(4096);

    prep_w<<<786432 / 256, 256, 0, stream>>>(Wih0, Whh0, W0c, 512, 1536, 786432);
    prep_w<<<1048576 / 256, 256, 0, stream>>>(Wih1, Whh1, W1c, 1024, 2048, 1048576);
    prep_misc2<<<(8192 + 2 * B_ * H_ + 255) / 256, 256, 0, stream>>>(
        h0in, bih0, bhh0, bih1, bhh1, bias0, bias1, h0A, h0B, h1A, h1B, bar);

    void* args[] = {(void*)&x, (void*)&W0c, (void*)&W1c, (void*)&bias0, (void*)&bias1,
                    (void*)&c0in, (void*)&h0A, (void*)&h0B, (void*)&h1A, (void*)&h1B,
                    (void*)&h1f, (void*)&bar};
    hipLaunchCooperativeKernel((void*)lstm_persist, dim3(256), dim3(512), args, 0, stream);

    fc_k<<<(64000 + 255) / 256, 256, 0, stream>>>(h1f, Wfc, bfc, out);
}